// Round 15
// baseline (71.508 us; speedup 1.0000x reference)
//
#include <hip/hip_runtime.h>
#include <hip/hip_bf16.h>
#include <stdint.h>

typedef __attribute__((ext_vector_type(8))) short short8;
typedef __attribute__((ext_vector_type(4))) float f32x4;

#define NTHREADS 256
#define DIM 128
#define NH 16
#define HD 8
#define HIDDEN 344
#define HIDP 352          // HIDDEN padded to multiple of 32 (22 col-tiles)
#define BATCH 4
#define SEQ 2048
#define MROWS (BATCH * SEQ)   // 8192
#define LOG2E 1.4426950408889634f

static __device__ __forceinline__ uint16_t f2bf(float f) {
  union { float f; uint32_t u; } v; v.f = f;
  uint32_t r = v.u + 0x7FFFu + ((v.u >> 16) & 1u);
  return (uint16_t)(r >> 16);
}
static __device__ __forceinline__ float fast_exp2(float x) {
#if __has_builtin(__builtin_amdgcn_exp2f)
  return __builtin_amdgcn_exp2f(x);
#else
  return exp2f(x);
#endif
}
// RNE pack: compiler emits v_cvt_pk_bf16_f32
static __device__ __forceinline__ uint32_t pk2(float lo, float hi) {
  union { __hip_bfloat162 b; uint32_t u; } c;
  c.b = __float22bfloat162_rn(make_float2(lo, hi));
  return c.u;
}
// truncating bf16x2 pack: one v_perm_b32 (p >= 0, error <= 2^-8 relative)
static __device__ __forceinline__ uint32_t pkt(float lo, float hi) {
  return __builtin_amdgcn_perm(__builtin_bit_cast(uint32_t, hi),
                               __builtin_bit_cast(uint32_t, lo), 0x07060302u);
}
static __device__ __forceinline__ f32x4 mfma32(short8 a, short8 b, f32x4 c) {
  return __builtin_amdgcn_mfma_f32_16x16x32_bf16(a, b, c, 0, 0, 0);
}

// ------------------------------------------------------------------
// prep: weights -> transposed bf16 Wt[n][k], padded where needed.
// wq rows pre-scaled by log2(e) so attention uses exp2 directly.
// ------------------------------------------------------------------
__global__ __launch_bounds__(256) void prep_kernel(
    const float* __restrict__ wq,
    const float* __restrict__ wk, const float* __restrict__ wv,
    const float* __restrict__ wo, const float* __restrict__ w1,
    const float* __restrict__ w3, const float* __restrict__ w2,
    uint16_t* __restrict__ qkv_t,
    uint16_t* __restrict__ wo_t,  uint16_t* __restrict__ w1_t,
    uint16_t* __restrict__ w3_t,  uint16_t* __restrict__ w2_t)
{
  const int nt  = gridDim.x * blockDim.x;
  const int tid = blockIdx.x * blockDim.x + threadIdx.x;
  for (int i = tid; i < 384 * 128; i += nt) {
    int n = i >> 7, k = i & 127;
    const float* w = (n < 128) ? wq : ((n < 256) ? wk : wv);
    const float s = (n < 128) ? LOG2E : 1.0f;
    qkv_t[i] = f2bf(w[k * 128 + (n & 127)] * s);
  }
  for (int i = tid; i < 128 * 128; i += nt) {
    int n = i >> 7, k = i & 127;
    wo_t[i] = f2bf(wo[k * 128 + n]);
  }
  for (int i = tid; i < 384 * 128; i += nt) {
    int n = i >> 7, k = i & 127;
    w1_t[i] = (n < HIDDEN) ? f2bf(w1[k * HIDDEN + n]) : (uint16_t)0;
    w3_t[i] = (n < HIDDEN) ? f2bf(w3[k * HIDDEN + n]) : (uint16_t)0;
  }
  for (int i = tid; i < 128 * HIDP; i += nt) {
    int n = i / HIDP, k = i - n * HIDP;
    w2_t[i] = (k < HIDDEN) ? f2bf(w2[k * 128 + n]) : (uint16_t)0;
  }
}

// ------------------------------------------------------------------
// Register-streaming QKV GEMM (r7-proven): no LDS, no barriers.
// ------------------------------------------------------------------
__global__ __launch_bounds__(256, 4) void qkv_gemm(
    const float* __restrict__ Av, const uint16_t* __restrict__ B1t,
    uint16_t* __restrict__ outb,
    uint16_t* __restrict__ kc_o, uint16_t* __restrict__ vt_o)
{
  const int tid = threadIdx.x;
  const int w = tid >> 6, l = tid & 63;
  const int lg = l >> 4, lm = l & 15;
  const int row0 = blockIdx.x * 64 + w * 16;
  const int col0 = blockIdx.y * 64;

  short8 af[4];
  const float* Af = Av + (size_t)(row0 + lm) * 128 + lg * 8;
#pragma unroll
  for (int ks = 0; ks < 4; ++ks) {
    const f32x4 a0 = *(const f32x4*)(Af + ks * 32);
    const f32x4 a1 = *(const f32x4*)(Af + ks * 32 + 4);
    union { uint32_t u[4]; short8 s8; } cv;
    cv.u[0] = pk2(a0[0], a0[1]); cv.u[1] = pk2(a0[2], a0[3]);
    cv.u[2] = pk2(a1[0], a1[1]); cv.u[3] = pk2(a1[2], a1[3]);
    af[ks] = cv.s8;
  }

  f32x4 acc[4];
#pragma unroll
  for (int t = 0; t < 4; ++t) acc[t] = (f32x4){0.f, 0.f, 0.f, 0.f};

#pragma unroll
  for (int t = 0; t < 4; ++t) {
    const uint16_t* Bp = B1t + (size_t)(col0 + t * 16 + lm) * 128 + lg * 8;
#pragma unroll
    for (int ks = 0; ks < 4; ++ks)
      acc[t] = mfma32(af[ks], *(const short8*)(Bp + ks * 32), acc[t]);
  }

#pragma unroll
  for (int t = 0; t < 4; ++t) {
#pragma unroll
    for (int r = 0; r < 4; ++r) {
      const int row = row0 + lg * 4 + r;
      const int col = col0 + t * 16 + lm;
      const float v = acc[t][r];
      const int bb = row >> 11, ss = row & 2047;
      if (col < 128) {
        outb[(size_t)row * 128 + col] = f2bf(v);            // Q (pre-scaled)
      } else if (col < 256) {
        const int c = col - 128;
        kc_o[((size_t)((bb << 4) + (c >> 3)) * SEQ + ss) * 8 + (c & 7)] = f2bf(v);
      } else {
        const int c = col - 256;
        vt_o[((size_t)(bb * 128 + c)) * SEQ + ss] = f2bf(v);
      }
    }
  }
}

// ------------------------------------------------------------------
// Flash attention (r14): 4 q-tiles/wave + 4-way key-split, cross-tile
// pipelined, single K/V buffers with deferred prefetch. ~37 us; three
// scheduling rewrites (r12-r14) were all null -> VGPR band caps it at
// 4 waves/SIMD; parked pending a structural idea.
// ------------------------------------------------------------------
__global__ __launch_bounds__(256, 4) void attn_kernel(
    const uint16_t* __restrict__ qb,   // [MROWS][128]  (pre-scaled Q)
    const uint16_t* __restrict__ kc,   // [B*NH][SEQ][8]
    const uint16_t* __restrict__ vt,   // [B*NH*8][SEQ]
    uint16_t* __restrict__ attn_o)     // [MROWS][128]
{
  __shared__ __attribute__((aligned(16))) float part[4][64][16];

  const int tid = threadIdx.x;
  const int w = tid >> 6, l = tid & 63;
  const int lg = l >> 4, lm = l & 15;
  int bid = blockIdx.x;
  bid = (bid & 7) * 256 + (bid >> 3);   // bijective XCD swizzle (2048 % 8 == 0)
  const int qc = bid & 31;              // SEQ/64 = 32 q-chunks
  const int bh = bid >> 5;
  const int b = bh >> 4, h = bh & 15;
  const int q0 = qc * 64;
  const int kh = w;                     // key quarter per wave

  const short8 zero8 = {0, 0, 0, 0, 0, 0, 0, 0};
  const f32x4 zero4 = {0.f, 0.f, 0.f, 0.f};
  const short ob = (short)0x3F80;  // bf16 1.0
  const short8 ones8 = {ob, ob, ob, ob, ob, ob, ob, ob};

  // Q fragments (4 tiles, same rows for all waves): lg==0 holds Q[q][d]
  short8 qf0 = zero8, qf1 = zero8, qf2 = zero8, qf3 = zero8;
  if (lg == 0) {
    const uint16_t* qp = qb + (size_t)(b * SEQ + q0 + lm) * DIM + h * HD;
    qf0 = *(const short8*)(qp);
    qf1 = *(const short8*)(qp + 16 * DIM);
    qf2 = *(const short8*)(qp + 32 * DIM);
    qf3 = *(const short8*)(qp + 48 * DIM);
  }

  // wave covers keys [kh*512, kh*512+512): 8 chunks of 64
  // permuted K base: tile-A row lm <- key 8*(lm>>2)+(lm&3)
  const uint16_t* kp = kc + (size_t)bh * SEQ * HD +
                       (kh * 512 + 8 * (lm >> 2) + (lm & 3)) * HD;
  // V: A-frag lane (lg, lm<8) holds Vt[d=lm][key + 8*lg + j]
  const uint16_t* vp = vt + (size_t)(bh * HD + (lm & 7)) * SEQ + kh * 512 + lg * 8;

  // single-buffer K/V, deferred prefetch
  short8 k0 = zero8, k1 = zero8, k2 = zero8, k3 = zero8;
  short8 v0 = (lm == 8) ? ones8 : zero8;
  short8 v1 = v0;

  f32x4 acc0 = zero4, acc1 = zero4, acc2 = zero4, acc3 = zero4;

#define LK()                                       \
  do { if (lg == 0) {                              \
    k0 = *(const short8*)(kp);                     \
    k1 = *(const short8*)(kp + 32);                \
    k2 = *(const short8*)(kp + 256);               \
    k3 = *(const short8*)(kp + 288); }             \
    kp += 512; } while (0)

#define LV()                                       \
  do { if (lm < HD) {                              \
    v0 = *(const short8*)(vp);                     \
    v1 = *(const short8*)(vp + 32); }              \
    vp += 64; } while (0)

#define PACKP(SA, SB, OUT)                                  \
  do { union { uint32_t u[4]; short8 s; } _t;               \
    _t.u[0] = pkt(fast_exp2(SA[0]), fast_exp2(SA[1]));      \
    _t.u[1] = pkt(fast_exp2(SA[2]), fast_exp2(SA[3]));      \
    _t.u[2] = pkt(fast_exp2(SB[0]), fast_exp2(SB[1]));      \
    _t.u[3] = pkt(fast_exp2(SB[2]), fast_exp2(SB[3]));      \
    OUT = _t.s; } while (0)

  // preload chunk 0
  LK();
  LV();

#pragma unroll 1
  for (int it = 0; it < 8; ++it) {
    short8 p0, p1;
    f32x4 sa0 = mfma32(k0, qf0, zero4);
    f32x4 sa1 = mfma32(k1, qf0, zero4);
    f32x4 sa2 = mfma32(k2, qf0, zero4);
    f32x4 sa3 = mfma32(k3, qf0, zero4);
    f32x4 sb0 = mfma32(k0, qf1, zero4);
    f32x4 sb1 = mfma32(k1, qf1, zero4);
    f32x4 sb2 = mfma32(k2, qf1, zero4);
    f32x4 sb3 = mfma32(k3, qf1, zero4);
    PACKP(sa0, sa1, p0);
    PACKP(sa2, sa3, p1);
    acc0 = mfma32(v0, p0, acc0);
    acc0 = mfma32(v1, p1, acc0);
    sa0 = mfma32(k0, qf2, zero4);
    sa1 = mfma32(k1, qf2, zero4);
    sa2 = mfma32(k2, qf2, zero4);
    sa3 = mfma32(k3, qf2, zero4);
    PACKP(sb0, sb1, p0);
    PACKP(sb2, sb3, p1);
    acc1 = mfma32(v0, p0, acc1);
    acc1 = mfma32(v1, p1, acc1);
    sb0 = mfma32(k0, qf3, zero4);
    sb1 = mfma32(k1, qf3, zero4);
    sb2 = mfma32(k2, qf3, zero4);
    sb3 = mfma32(k3, qf3, zero4);
    LK();   // next chunk's K (WAR-safe: all QK issued)
    PACKP(sa0, sa1, p0);
    PACKP(sa2, sa3, p1);
    acc2 = mfma32(v0, p0, acc2);
    acc2 = mfma32(v1, p1, acc2);
    PACKP(sb0, sb1, p0);
    PACKP(sb2, sb3, p1);
    acc3 = mfma32(v0, p0, acc3);
    acc3 = mfma32(v1, p1, acc3);
    LV();   // next chunk's V (V regs dead after acc3 PV)
  }

#undef LK
#undef LV
#undef PACKP

  // ---- merge the four key-quarters (pure addition; no-max softmax) ----
  *(f32x4*)&part[w][l][0]  = acc0;
  *(f32x4*)&part[w][l][4]  = acc1;
  *(f32x4*)&part[w][l][8]  = acc2;
  *(f32x4*)&part[w][l][12] = acc3;
  __syncthreads();

  // wave w merges tile w across the 4 key-quarters
  {
    const f32x4 m = (*(const f32x4*)&part[0][l][w * 4] +
                     *(const f32x4*)&part[1][l][w * 4]) +
                    (*(const f32x4*)&part[2][l][w * 4] +
                     *(const f32x4*)&part[3][l][w * 4]);
    // row 8 (lane 32+lm, reg 0) holds sum(p) for q=lm
    const float inv = 1.0f / __shfl(m[0], 32 + lm);
    if (lg < 2) {
      const size_t o = (size_t)(b * SEQ + q0 + w * 16 + lm) * DIM + h * HD + lg * 4;
      *(uint32_t*)(attn_o + o)     = pk2(m[0] * inv, m[1] * inv);
      *(uint32_t*)(attn_o + o + 2) = pk2(m[2] * inv, m[3] * inv);
    }
  }
}

// ------------------------------------------------------------------
// Fused post-attention chain, 16-WAVE blocks for TLP (ffn was ~19.6us
// at 4 waves/SIMD, latency-bound on L2 B-operand loads; working set
// ~50 VGPR << attn's, so it CAN sit in the 8-wave/SIMD band).
// Block = 16 rows x 16 waves (1024 thr); __launch_bounds__(1024,8)
// -> VGPR cap 64 -> 2 blocks/CU = 32 waves/CU = 8 waves/SIMD.
//   A: h = x + attn@wo   -> waves 0-7, ct = w; h -> LDS + hreg
//   B: u = silu(h@w1)*(h@w3) -> all 16 waves: ct = w (+ w+16 if w<6)
//   C: out = h + u@w2    -> waves 0-7, ct = w (hreg owner matches)
// 2 barriers; LDS 15.9 KB (strides 136/360 break bank conflicts).
// ------------------------------------------------------------------
__global__ __launch_bounds__(1024, 8) void ffn_kernel(
    const uint16_t* __restrict__ attn_o,  // [MROWS][128] bf16
    const float* __restrict__ x,          // [MROWS][128] fp32
    const uint16_t* __restrict__ wo_t,    // [128][128]
    const uint16_t* __restrict__ w1_t,    // [384][128] (rows>=344 zero)
    const uint16_t* __restrict__ w3_t,    // [384][128]
    const uint16_t* __restrict__ w2_t,    // [128][352] (k>=344 zero)
    float* __restrict__ out)              // [MROWS][128] fp32
{
  __shared__ __attribute__((aligned(16))) uint16_t h_l[16][136];
  __shared__ __attribute__((aligned(16))) uint16_t u_l[16][360];

  const int tid = threadIdx.x;
  const int w = tid >> 6, l = tid & 63;   // w = 0..15
  const int lg = l >> 4, lm = l & 15;
  const int R0 = blockIdx.x * 16;

  // ---- stage A: h = x + attn @ wo  (waves 0-7, ct = w) ----
  float hreg[4];
  if (w < 8) {
    short8 af[4];
    const uint16_t* Ap = attn_o + (size_t)(R0 + lm) * 128 + lg * 8;
#pragma unroll
    for (int ks = 0; ks < 4; ++ks) af[ks] = *(const short8*)(Ap + ks * 32);

    f32x4 acc = (f32x4){0.f, 0.f, 0.f, 0.f};
    const uint16_t* Bp = wo_t + (size_t)(w * 16 + lm) * 128 + lg * 8;
#pragma unroll
    for (int ks = 0; ks < 4; ++ks)
      acc = mfma32(af[ks], *(const short8*)(Bp + ks * 32), acc);
#pragma unroll
    for (int r = 0; r < 4; ++r) {
      const float h = acc[r] + x[(size_t)(R0 + lg * 4 + r) * 128 + w * 16 + lm];
      hreg[r] = h;
      h_l[lg * 4 + r][w * 16 + lm] = f2bf(h);
    }
  }
  __syncthreads();

  // ---- stage B: u = silu(h@w1)*(h@w3)  (all 16 waves) ----
  short8 af2[4];
#pragma unroll
  for (int ks = 0; ks < 4; ++ks)
    af2[ks] = *(const short8*)&h_l[lm][ks * 32 + lg * 8];

  {
    const int ct = w;   // ct 0..15
    f32x4 ag = (f32x4){0.f, 0.f, 0.f, 0.f};
    f32x4 ae = (f32x4){0.f, 0.f, 0.f, 0.f};
    const uint16_t* B1p = w1_t + (size_t)(ct * 16 + lm) * 128 + lg * 8;
    const uint16_t* B3p = w3_t + (size_t)(ct * 16 + lm) * 128 + lg * 8;
#pragma unroll
    for (int ks = 0; ks < 4; ++ks) {
      ag = mfma32(af2[ks], *(const short8*)(B1p + ks * 32), ag);
      ae = mfma32(af2[ks], *(const short8*)(B3p + ks * 32), ae);
    }
#pragma unroll
    for (int r = 0; r < 4; ++r) {
      const float g = ag[r];
      const float u = g / (1.f + __expf(-g)) * ae[r];
      u_l[lg * 4 + r][ct * 16 + lm] = f2bf(u);
    }
  }
  if (w < 6) {
    const int ct = w + 16;   // ct 16..21
    f32x4 ag = (f32x4){0.f, 0.f, 0.f, 0.f};
    f32x4 ae = (f32x4){0.f, 0.f, 0.f, 0.f};
    const uint16_t* B1p = w1_t + (size_t)(ct * 16 + lm) * 128 + lg * 8;
    const uint16_t* B3p = w3_t + (size_t)(ct * 16 + lm) * 128 + lg * 8;
#pragma unroll
    for (int ks = 0; ks < 4; ++ks) {
      ag = mfma32(af2[ks], *(const short8*)(B1p + ks * 32), ag);
      ae = mfma32(af2[ks], *(const short8*)(B3p + ks * 32), ae);
    }
#pragma unroll
    for (int r = 0; r < 4; ++r) {
      const float g = ag[r];
      const float u = g / (1.f + __expf(-g)) * ae[r];
      u_l[lg * 4 + r][ct * 16 + lm] = f2bf(u);
    }
  }
  __syncthreads();

  // ---- stage C: out = h + u @ w2  (waves 0-7, ct = w) ----
  if (w < 8) {
    f32x4 acc = (f32x4){0.f, 0.f, 0.f, 0.f};
    const uint16_t* Bp = w2_t + (size_t)(w * 16 + lm) * HIDP + lg * 8;
#pragma unroll
    for (int k2 = 0; k2 < 11; ++k2) {
      const short8 a3 = *(const short8*)&u_l[lm][k2 * 32 + lg * 8];
      acc = mfma32(a3, *(const short8*)(Bp + k2 * 32), acc);
    }
#pragma unroll
    for (int r = 0; r < 4; ++r)
      out[(size_t)(R0 + lg * 4 + r) * 128 + w * 16 + lm] = hreg[r] + acc[r];
  }
}

// ------------------------------------------------------------------
extern "C" void kernel_launch(void* const* d_in, const int* in_sizes, int n_in,
                              void* d_out, int out_size, void* d_ws, size_t ws_size,
                              hipStream_t stream) {
  const float* x  = (const float*)d_in[0];
  const float* wq = (const float*)d_in[1];
  const float* wk = (const float*)d_in[2];
  const float* wv = (const float*)d_in[3];
  const float* wo = (const float*)d_in[4];
  const float* w1 = (const float*)d_in[5];
  const float* w3 = (const float*)d_in[6];
  const float* w2 = (const float*)d_in[7];
  float* out = (float*)d_out;

  char* ws = (char*)d_ws;
  size_t off = 0;
  auto alloc = [&](size_t bytes) {
    size_t o = off;
    off += (bytes + 255) & ~(size_t)255;
    return o;
  };
  uint16_t* qkv_t  = (uint16_t*)(ws + alloc(384 * 128 * 2));
  uint16_t* wo_t   = (uint16_t*)(ws + alloc(128 * 128 * 2));
  uint16_t* w1_t   = (uint16_t*)(ws + alloc(384 * 128 * 2));
  uint16_t* w3_t   = (uint16_t*)(ws + alloc(384 * 128 * 2));
  uint16_t* w2_t   = (uint16_t*)(ws + alloc(128 * HIDP * 2));
  uint16_t* q_buf  = (uint16_t*)(ws + alloc((size_t)MROWS * DIM * 2));
  uint16_t* kc_b   = (uint16_t*)(ws + alloc((size_t)MROWS * DIM * 2));
  uint16_t* vt_b   = (uint16_t*)(ws + alloc((size_t)MROWS * DIM * 2));
  uint16_t* attn_o = (uint16_t*)(ws + alloc((size_t)MROWS * DIM * 2));

  prep_kernel<<<512, 256, 0, stream>>>(wq, wk, wv, wo, w1, w3, w2,
                                       qkv_t, wo_t, w1_t, w3_t, w2_t);
  // qkv = x @ [wq*log2e | wk | wv] -> q_buf, Kc, Vt
  qkv_gemm<<<dim3(MROWS / 64, 6), 256, 0, stream>>>(
      x, qkv_t, q_buf, kc_b, vt_b);
  // flash attention: 2048 blocks, 4 q-tiles/wave, 4-way key split
  attn_kernel<<<dim3(BATCH * NH * (SEQ / 64)), 256, 0, stream>>>(
      q_buf, kc_b, vt_b, attn_o);
  // fused: h = x + attn@wo; out = h + silu(h@w1)*(h@w3)@w2
  // 512 blocks x 1024 threads (16 waves), 8 waves/SIMD target
  ffn_kernel<<<dim3(MROWS / 16), 1024, 0, stream>>>(
      attn_o, x, wo_t, w1_t, w3_t, w2_t, out);
}

// Round 16
// 70.745 us; speedup vs baseline: 1.0108x; 1.0108x over previous
//
#include <hip/hip_runtime.h>
#include <hip/hip_bf16.h>
#include <stdint.h>

typedef __attribute__((ext_vector_type(8))) short short8;
typedef __attribute__((ext_vector_type(4))) float f32x4;

#define NTHREADS 256
#define DIM 128
#define NH 16
#define HD 8
#define HIDDEN 344
#define HIDP 352          // HIDDEN padded to multiple of 32 (22 col-tiles)
#define BATCH 4
#define SEQ 2048
#define MROWS (BATCH * SEQ)   // 8192
#define LOG2E 1.4426950408889634f

static __device__ __forceinline__ uint16_t f2bf(float f) {
  union { float f; uint32_t u; } v; v.f = f;
  uint32_t r = v.u + 0x7FFFu + ((v.u >> 16) & 1u);
  return (uint16_t)(r >> 16);
}
static __device__ __forceinline__ float fast_exp2(float x) {
#if __has_builtin(__builtin_amdgcn_exp2f)
  return __builtin_amdgcn_exp2f(x);
#else
  return exp2f(x);
#endif
}
// RNE pack: compiler emits v_cvt_pk_bf16_f32
static __device__ __forceinline__ uint32_t pk2(float lo, float hi) {
  union { __hip_bfloat162 b; uint32_t u; } c;
  c.b = __float22bfloat162_rn(make_float2(lo, hi));
  return c.u;
}
// truncating bf16x2 pack: one v_perm_b32 (p >= 0, error <= 2^-8 relative)
static __device__ __forceinline__ uint32_t pkt(float lo, float hi) {
  return __builtin_amdgcn_perm(__builtin_bit_cast(uint32_t, hi),
                               __builtin_bit_cast(uint32_t, lo), 0x07060302u);
}
static __device__ __forceinline__ f32x4 mfma32(short8 a, short8 b, f32x4 c) {
  return __builtin_amdgcn_mfma_f32_16x16x32_bf16(a, b, c, 0, 0, 0);
}

// ------------------------------------------------------------------
// prep: weights -> transposed bf16 Wt[n][k], padded where needed.
// wq rows pre-scaled by log2(e) so attention uses exp2 directly.
// ------------------------------------------------------------------
__global__ __launch_bounds__(256) void prep_kernel(
    const float* __restrict__ wq,
    const float* __restrict__ wk, const float* __restrict__ wv,
    const float* __restrict__ wo, const float* __restrict__ w1,
    const float* __restrict__ w3, const float* __restrict__ w2,
    uint16_t* __restrict__ qkv_t,
    uint16_t* __restrict__ wo_t,  uint16_t* __restrict__ w1_t,
    uint16_t* __restrict__ w3_t,  uint16_t* __restrict__ w2_t)
{
  const int nt  = gridDim.x * blockDim.x;
  const int tid = blockIdx.x * blockDim.x + threadIdx.x;
  for (int i = tid; i < 384 * 128; i += nt) {
    int n = i >> 7, k = i & 127;
    const float* w = (n < 128) ? wq : ((n < 256) ? wk : wv);
    const float s = (n < 128) ? LOG2E : 1.0f;
    qkv_t[i] = f2bf(w[k * 128 + (n & 127)] * s);
  }
  for (int i = tid; i < 128 * 128; i += nt) {
    int n = i >> 7, k = i & 127;
    wo_t[i] = f2bf(wo[k * 128 + n]);
  }
  for (int i = tid; i < 384 * 128; i += nt) {
    int n = i >> 7, k = i & 127;
    w1_t[i] = (n < HIDDEN) ? f2bf(w1[k * HIDDEN + n]) : (uint16_t)0;
    w3_t[i] = (n < HIDDEN) ? f2bf(w3[k * HIDDEN + n]) : (uint16_t)0;
  }
  for (int i = tid; i < 128 * HIDP; i += nt) {
    int n = i / HIDP, k = i - n * HIDP;
    w2_t[i] = (k < HIDDEN) ? f2bf(w2[k * 128 + n]) : (uint16_t)0;
  }
}

// ------------------------------------------------------------------
// Register-streaming QKV GEMM (r7-proven): no LDS, no barriers.
// ------------------------------------------------------------------
__global__ __launch_bounds__(256, 4) void qkv_gemm(
    const float* __restrict__ Av, const uint16_t* __restrict__ B1t,
    uint16_t* __restrict__ outb,
    uint16_t* __restrict__ kc_o, uint16_t* __restrict__ vt_o)
{
  const int tid = threadIdx.x;
  const int w = tid >> 6, l = tid & 63;
  const int lg = l >> 4, lm = l & 15;
  const int row0 = blockIdx.x * 64 + w * 16;
  const int col0 = blockIdx.y * 64;

  short8 af[4];
  const float* Af = Av + (size_t)(row0 + lm) * 128 + lg * 8;
#pragma unroll
  for (int ks = 0; ks < 4; ++ks) {
    const f32x4 a0 = *(const f32x4*)(Af + ks * 32);
    const f32x4 a1 = *(const f32x4*)(Af + ks * 32 + 4);
    union { uint32_t u[4]; short8 s8; } cv;
    cv.u[0] = pk2(a0[0], a0[1]); cv.u[1] = pk2(a0[2], a0[3]);
    cv.u[2] = pk2(a1[0], a1[1]); cv.u[3] = pk2(a1[2], a1[3]);
    af[ks] = cv.s8;
  }

  f32x4 acc[4];
#pragma unroll
  for (int t = 0; t < 4; ++t) acc[t] = (f32x4){0.f, 0.f, 0.f, 0.f};

#pragma unroll
  for (int t = 0; t < 4; ++t) {
    const uint16_t* Bp = B1t + (size_t)(col0 + t * 16 + lm) * 128 + lg * 8;
#pragma unroll
    for (int ks = 0; ks < 4; ++ks)
      acc[t] = mfma32(af[ks], *(const short8*)(Bp + ks * 32), acc[t]);
  }

#pragma unroll
  for (int t = 0; t < 4; ++t) {
#pragma unroll
    for (int r = 0; r < 4; ++r) {
      const int row = row0 + lg * 4 + r;
      const int col = col0 + t * 16 + lm;
      const float v = acc[t][r];
      const int bb = row >> 11, ss = row & 2047;
      if (col < 128) {
        outb[(size_t)row * 128 + col] = f2bf(v);            // Q (pre-scaled)
      } else if (col < 256) {
        const int c = col - 128;
        kc_o[((size_t)((bb << 4) + (c >> 3)) * SEQ + ss) * 8 + (c & 7)] = f2bf(v);
      } else {
        const int c = col - 256;
        vt_o[((size_t)(bb * 128 + c)) * SEQ + ss] = f2bf(v);
      }
    }
  }
}

// ------------------------------------------------------------------
// Flash attention (r14): 4 q-tiles/wave + 4-way key-split, cross-tile
// pipelined, single K/V buffers with deferred prefetch. ~35 us; three
// scheduling rewrites (r12-r14) were all null -> parked.
// ------------------------------------------------------------------
__global__ __launch_bounds__(256, 4) void attn_kernel(
    const uint16_t* __restrict__ qb,   // [MROWS][128]  (pre-scaled Q)
    const uint16_t* __restrict__ kc,   // [B*NH][SEQ][8]
    const uint16_t* __restrict__ vt,   // [B*NH*8][SEQ]
    uint16_t* __restrict__ attn_o)     // [MROWS][128]
{
  __shared__ __attribute__((aligned(16))) float part[4][64][16];

  const int tid = threadIdx.x;
  const int w = tid >> 6, l = tid & 63;
  const int lg = l >> 4, lm = l & 15;
  int bid = blockIdx.x;
  bid = (bid & 7) * 256 + (bid >> 3);   // bijective XCD swizzle (2048 % 8 == 0)
  const int qc = bid & 31;              // SEQ/64 = 32 q-chunks
  const int bh = bid >> 5;
  const int b = bh >> 4, h = bh & 15;
  const int q0 = qc * 64;
  const int kh = w;                     // key quarter per wave

  const short8 zero8 = {0, 0, 0, 0, 0, 0, 0, 0};
  const f32x4 zero4 = {0.f, 0.f, 0.f, 0.f};
  const short ob = (short)0x3F80;  // bf16 1.0
  const short8 ones8 = {ob, ob, ob, ob, ob, ob, ob, ob};

  // Q fragments (4 tiles, same rows for all waves): lg==0 holds Q[q][d]
  short8 qf0 = zero8, qf1 = zero8, qf2 = zero8, qf3 = zero8;
  if (lg == 0) {
    const uint16_t* qp = qb + (size_t)(b * SEQ + q0 + lm) * DIM + h * HD;
    qf0 = *(const short8*)(qp);
    qf1 = *(const short8*)(qp + 16 * DIM);
    qf2 = *(const short8*)(qp + 32 * DIM);
    qf3 = *(const short8*)(qp + 48 * DIM);
  }

  // wave covers keys [kh*512, kh*512+512): 8 chunks of 64
  // permuted K base: tile-A row lm <- key 8*(lm>>2)+(lm&3)
  const uint16_t* kp = kc + (size_t)bh * SEQ * HD +
                       (kh * 512 + 8 * (lm >> 2) + (lm & 3)) * HD;
  // V: A-frag lane (lg, lm<8) holds Vt[d=lm][key + 8*lg + j]
  const uint16_t* vp = vt + (size_t)(bh * HD + (lm & 7)) * SEQ + kh * 512 + lg * 8;

  // single-buffer K/V, deferred prefetch
  short8 k0 = zero8, k1 = zero8, k2 = zero8, k3 = zero8;
  short8 v0 = (lm == 8) ? ones8 : zero8;
  short8 v1 = v0;

  f32x4 acc0 = zero4, acc1 = zero4, acc2 = zero4, acc3 = zero4;

#define LK()                                       \
  do { if (lg == 0) {                              \
    k0 = *(const short8*)(kp);                     \
    k1 = *(const short8*)(kp + 32);                \
    k2 = *(const short8*)(kp + 256);               \
    k3 = *(const short8*)(kp + 288); }             \
    kp += 512; } while (0)

#define LV()                                       \
  do { if (lm < HD) {                              \
    v0 = *(const short8*)(vp);                     \
    v1 = *(const short8*)(vp + 32); }              \
    vp += 64; } while (0)

#define PACKP(SA, SB, OUT)                                  \
  do { union { uint32_t u[4]; short8 s; } _t;               \
    _t.u[0] = pkt(fast_exp2(SA[0]), fast_exp2(SA[1]));      \
    _t.u[1] = pkt(fast_exp2(SA[2]), fast_exp2(SA[3]));      \
    _t.u[2] = pkt(fast_exp2(SB[0]), fast_exp2(SB[1]));      \
    _t.u[3] = pkt(fast_exp2(SB[2]), fast_exp2(SB[3]));      \
    OUT = _t.s; } while (0)

  // preload chunk 0
  LK();
  LV();

#pragma unroll 1
  for (int it = 0; it < 8; ++it) {
    short8 p0, p1;
    f32x4 sa0 = mfma32(k0, qf0, zero4);
    f32x4 sa1 = mfma32(k1, qf0, zero4);
    f32x4 sa2 = mfma32(k2, qf0, zero4);
    f32x4 sa3 = mfma32(k3, qf0, zero4);
    f32x4 sb0 = mfma32(k0, qf1, zero4);
    f32x4 sb1 = mfma32(k1, qf1, zero4);
    f32x4 sb2 = mfma32(k2, qf1, zero4);
    f32x4 sb3 = mfma32(k3, qf1, zero4);
    PACKP(sa0, sa1, p0);
    PACKP(sa2, sa3, p1);
    acc0 = mfma32(v0, p0, acc0);
    acc0 = mfma32(v1, p1, acc0);
    sa0 = mfma32(k0, qf2, zero4);
    sa1 = mfma32(k1, qf2, zero4);
    sa2 = mfma32(k2, qf2, zero4);
    sa3 = mfma32(k3, qf2, zero4);
    PACKP(sb0, sb1, p0);
    PACKP(sb2, sb3, p1);
    acc1 = mfma32(v0, p0, acc1);
    acc1 = mfma32(v1, p1, acc1);
    sb0 = mfma32(k0, qf3, zero4);
    sb1 = mfma32(k1, qf3, zero4);
    sb2 = mfma32(k2, qf3, zero4);
    sb3 = mfma32(k3, qf3, zero4);
    LK();   // next chunk's K (WAR-safe: all QK issued)
    PACKP(sa0, sa1, p0);
    PACKP(sa2, sa3, p1);
    acc2 = mfma32(v0, p0, acc2);
    acc2 = mfma32(v1, p1, acc2);
    PACKP(sb0, sb1, p0);
    PACKP(sb2, sb3, p1);
    acc3 = mfma32(v0, p0, acc3);
    acc3 = mfma32(v1, p1, acc3);
    LV();   // next chunk's V (V regs dead after acc3 PV)
  }

#undef LK
#undef LV
#undef PACKP

  // ---- merge the four key-quarters (pure addition; no-max softmax) ----
  *(f32x4*)&part[w][l][0]  = acc0;
  *(f32x4*)&part[w][l][4]  = acc1;
  *(f32x4*)&part[w][l][8]  = acc2;
  *(f32x4*)&part[w][l][12] = acc3;
  __syncthreads();

  // wave w merges tile w across the 4 key-quarters
  {
    const f32x4 m = (*(const f32x4*)&part[0][l][w * 4] +
                     *(const f32x4*)&part[1][l][w * 4]) +
                    (*(const f32x4*)&part[2][l][w * 4] +
                     *(const f32x4*)&part[3][l][w * 4]);
    // row 8 (lane 32+lm, reg 0) holds sum(p) for q=lm
    const float inv = 1.0f / __shfl(m[0], 32 + lm);
    if (lg < 2) {
      const size_t o = (size_t)(b * SEQ + q0 + w * 16 + lm) * DIM + h * HD + lg * 4;
      *(uint32_t*)(attn_o + o)     = pk2(m[0] * inv, m[1] * inv);
      *(uint32_t*)(attn_o + o + 2) = pk2(m[2] * inv, m[3] * inv);
    }
  }
}

// ------------------------------------------------------------------
// Fused post-attention chain, column-split (r10 shape) + WEIGHT
// PREFETCH: r15 proved ffn is latency-bound per wave (16-wave TLP was
// null), so issue the weight-fragment loads EARLY instead:
//  - entry: attn_o A-frags, wo frags, AND stage-B ct=w's w1/w3 frags
//    (their ~200cy L2 latency hides under stage A's ~700cy compute)
//  - ct=w+8 / w+16 frags issue right after the first B-MFMA cluster
//  - stage-C w2 frags issue immediately after the stage-B barrier
// Block = 16 rows x 8 waves (512 thr); grid 512 = 2 blocks/CU.
// __launch_bounds__(512,4): VGPR cap 128 vs ~90 working set (safe).
// ------------------------------------------------------------------
__global__ __launch_bounds__(512, 4) void ffn_kernel(
    const uint16_t* __restrict__ attn_o,  // [MROWS][128] bf16
    const float* __restrict__ x,          // [MROWS][128] fp32
    const uint16_t* __restrict__ wo_t,    // [128][128]
    const uint16_t* __restrict__ w1_t,    // [384][128] (rows>=344 zero)
    const uint16_t* __restrict__ w3_t,    // [384][128]
    const uint16_t* __restrict__ w2_t,    // [128][352] (k>=344 zero)
    float* __restrict__ out)              // [MROWS][128] fp32
{
  __shared__ __attribute__((aligned(16))) uint16_t h_l[16][136];
  __shared__ __attribute__((aligned(16))) uint16_t u_l[16][360];

  const int tid = threadIdx.x;
  const int w = tid >> 6, l = tid & 63;
  const int lg = l >> 4, lm = l & 15;
  const int R0 = blockIdx.x * 16;

  // ---- entry prefetch: A-frags, wo frags, stage-B ct=w weight frags ----
  short8 af[4], wof[4], b1a[4], b3a[4];
  {
    const uint16_t* Ap = attn_o + (size_t)(R0 + lm) * 128 + lg * 8;
    const uint16_t* Bp = wo_t + (size_t)(w * 16 + lm) * 128 + lg * 8;
    const uint16_t* B1p = w1_t + (size_t)(w * 16 + lm) * 128 + lg * 8;
    const uint16_t* B3p = w3_t + (size_t)(w * 16 + lm) * 128 + lg * 8;
#pragma unroll
    for (int ks = 0; ks < 4; ++ks) {
      af[ks]  = *(const short8*)(Ap + ks * 32);
      wof[ks] = *(const short8*)(Bp + ks * 32);
      b1a[ks] = *(const short8*)(B1p + ks * 32);
      b3a[ks] = *(const short8*)(B3p + ks * 32);
    }
  }

  // ---- stage A: h = x + attn @ wo  (wave w -> col-tile w) ----
  float hreg[4];
  {
    f32x4 acc = (f32x4){0.f, 0.f, 0.f, 0.f};
#pragma unroll
    for (int ks = 0; ks < 4; ++ks)
      acc = mfma32(af[ks], wof[ks], acc);
#pragma unroll
    for (int r = 0; r < 4; ++r) {
      const float h = acc[r] + x[(size_t)(R0 + lg * 4 + r) * 128 + w * 16 + lm];
      hreg[r] = h;
      h_l[lg * 4 + r][w * 16 + lm] = f2bf(h);
    }
  }
  __syncthreads();

  // ---- stage B: u = silu(h@w1)*(h@w3)  (wave w -> ct = w, w+8, w+16) ----
  short8 af2[4];
#pragma unroll
  for (int ks = 0; ks < 4; ++ks)
    af2[ks] = *(const short8*)&h_l[lm][ks * 32 + lg * 8];

  // ct = w (weights already in regs)
  {
    f32x4 ag = (f32x4){0.f, 0.f, 0.f, 0.f};
    f32x4 ae = (f32x4){0.f, 0.f, 0.f, 0.f};
#pragma unroll
    for (int ks = 0; ks < 4; ++ks) {
      ag = mfma32(af2[ks], b1a[ks], ag);
      ae = mfma32(af2[ks], b3a[ks], ae);
    }
    // prefetch ct = w+8 while the MFMAs above are in flight
    const int ct2 = w + 8;
    const uint16_t* B1p = w1_t + (size_t)(ct2 * 16 + lm) * 128 + lg * 8;
    const uint16_t* B3p = w3_t + (size_t)(ct2 * 16 + lm) * 128 + lg * 8;
#pragma unroll
    for (int ks = 0; ks < 4; ++ks) {
      b1a[ks] = *(const short8*)(B1p + ks * 32);
      b3a[ks] = *(const short8*)(B3p + ks * 32);
    }
#pragma unroll
    for (int r = 0; r < 4; ++r) {
      const float g = ag[r];
      const float u = g / (1.f + __expf(-g)) * ae[r];
      u_l[lg * 4 + r][w * 16 + lm] = f2bf(u);
    }
  }
  // ct = w+8 (prefetched)
  {
    const int ct = w + 8;
    f32x4 ag = (f32x4){0.f, 0.f, 0.f, 0.f};
    f32x4 ae = (f32x4){0.f, 0.f, 0.f, 0.f};
#pragma unroll
    for (int ks = 0; ks < 4; ++ks) {
      ag = mfma32(af2[ks], b1a[ks], ag);
      ae = mfma32(af2[ks], b3a[ks], ae);
    }
    if (w < 6) {   // prefetch ct = w+16
      const int ct3 = w + 16;
      const uint16_t* B1p = w1_t + (size_t)(ct3 * 16 + lm) * 128 + lg * 8;
      const uint16_t* B3p = w3_t + (size_t)(ct3 * 16 + lm) * 128 + lg * 8;
#pragma unroll
      for (int ks = 0; ks < 4; ++ks) {
        b1a[ks] = *(const short8*)(B1p + ks * 32);
        b3a[ks] = *(const short8*)(B3p + ks * 32);
      }
    }
#pragma unroll
    for (int r = 0; r < 4; ++r) {
      const float g = ag[r];
      const float u = g / (1.f + __expf(-g)) * ae[r];
      u_l[lg * 4 + r][ct * 16 + lm] = f2bf(u);
    }
  }
  if (w < 6) {   // ct = w+16 (prefetched)
    const int ct = w + 16;
    f32x4 ag = (f32x4){0.f, 0.f, 0.f, 0.f};
    f32x4 ae = (f32x4){0.f, 0.f, 0.f, 0.f};
#pragma unroll
    for (int ks = 0; ks < 4; ++ks) {
      ag = mfma32(af2[ks], b1a[ks], ag);
      ae = mfma32(af2[ks], b3a[ks], ae);
    }
#pragma unroll
    for (int r = 0; r < 4; ++r) {
      const float g = ag[r];
      const float u = g / (1.f + __expf(-g)) * ae[r];
      u_l[lg * 4 + r][ct * 16 + lm] = f2bf(u);
    }
  }
  __syncthreads();

  // ---- stage C: out = h + u @ w2  (wave w -> col-tile w) ----
  {
    // issue all 11 w2 fragment loads first (they don't depend on u_l)
    short8 w2f0, w2f1, w2f2, w2f3;
    const uint16_t* Bp = w2_t + (size_t)(w * 16 + lm) * HIDP + lg * 8;
    w2f0 = *(const short8*)(Bp);
    w2f1 = *(const short8*)(Bp + 32);
    w2f2 = *(const short8*)(Bp + 64);
    w2f3 = *(const short8*)(Bp + 96);
    f32x4 acc = (f32x4){0.f, 0.f, 0.f, 0.f};
    acc = mfma32(*(const short8*)&u_l[lm][0 * 32 + lg * 8], w2f0, acc);
    w2f0 = *(const short8*)(Bp + 128);
    acc = mfma32(*(const short8*)&u_l[lm][1 * 32 + lg * 8], w2f1, acc);
    w2f1 = *(const short8*)(Bp + 160);
    acc = mfma32(*(const short8*)&u_l[lm][2 * 32 + lg * 8], w2f2, acc);
    w2f2 = *(const short8*)(Bp + 192);
    acc = mfma32(*(const short8*)&u_l[lm][3 * 32 + lg * 8], w2f3, acc);
    w2f3 = *(const short8*)(Bp + 224);
    acc = mfma32(*(const short8*)&u_l[lm][4 * 32 + lg * 8], w2f0, acc);
    w2f0 = *(const short8*)(Bp + 256);
    acc = mfma32(*(const short8*)&u_l[lm][5 * 32 + lg * 8], w2f1, acc);
    w2f1 = *(const short8*)(Bp + 288);
    acc = mfma32(*(const short8*)&u_l[lm][6 * 32 + lg * 8], w2f2, acc);
    w2f2 = *(const short8*)(Bp + 320);
    acc = mfma32(*(const short8*)&u_l[lm][7 * 32 + lg * 8], w2f3, acc);
    acc = mfma32(*(const short8*)&u_l[lm][8 * 32 + lg * 8], w2f0, acc);
    acc = mfma32(*(const short8*)&u_l[lm][9 * 32 + lg * 8], w2f1, acc);
    acc = mfma32(*(const short8*)&u_l[lm][10 * 32 + lg * 8], w2f2, acc);
#pragma unroll
    for (int r = 0; r < 4; ++r)
      out[(size_t)(R0 + lg * 4 + r) * 128 + w * 16 + lm] = hreg[r] + acc[r];
  }
}

// ------------------------------------------------------------------
extern "C" void kernel_launch(void* const* d_in, const int* in_sizes, int n_in,
                              void* d_out, int out_size, void* d_ws, size_t ws_size,
                              hipStream_t stream) {
  const float* x  = (const float*)d_in[0];
  const float* wq = (const float*)d_in[1];
  const float* wk = (const float*)d_in[2];
  const float* wv = (const float*)d_in[3];
  const float* wo = (const float*)d_in[4];
  const float* w1 = (const float*)d_in[5];
  const float* w3 = (const float*)d_in[6];
  const float* w2 = (const float*)d_in[7];
  float* out = (float*)d_out;

  char* ws = (char*)d_ws;
  size_t off = 0;
  auto alloc = [&](size_t bytes) {
    size_t o = off;
    off += (bytes + 255) & ~(size_t)255;
    return o;
  };
  uint16_t* qkv_t  = (uint16_t*)(ws + alloc(384 * 128 * 2));
  uint16_t* wo_t   = (uint16_t*)(ws + alloc(128 * 128 * 2));
  uint16_t* w1_t   = (uint16_t*)(ws + alloc(384 * 128 * 2));
  uint16_t* w3_t   = (uint16_t*)(ws + alloc(384 * 128 * 2));
  uint16_t* w2_t   = (uint16_t*)(ws + alloc(128 * HIDP * 2));
  uint16_t* q_buf  = (uint16_t*)(ws + alloc((size_t)MROWS * DIM * 2));
  uint16_t* kc_b   = (uint16_t*)(ws + alloc((size_t)MROWS * DIM * 2));
  uint16_t* vt_b   = (uint16_t*)(ws + alloc((size_t)MROWS * DIM * 2));
  uint16_t* attn_o = (uint16_t*)(ws + alloc((size_t)MROWS * DIM * 2));

  prep_kernel<<<512, 256, 0, stream>>>(wq, wk, wv, wo, w1, w3, w2,
                                       qkv_t, wo_t, w1_t, w3_t, w2_t);
  // qkv = x @ [wq*log2e | wk | wv] -> q_buf, Kc, Vt
  qkv_gemm<<<dim3(MROWS / 64, 6), 256, 0, stream>>>(
      x, qkv_t, q_buf, kc_b, vt_b);
  // flash attention: 2048 blocks, 4 q-tiles/wave, 4-way key split
  attn_kernel<<<dim3(BATCH * NH * (SEQ / 64)), 256, 0, stream>>>(
      q_buf, kc_b, vt_b, attn_o);
  // fused: h = x + attn@wo; out = h + silu(h@w1)*(h@w3)@w2
  // 512 blocks x 512 threads, column-split waves + weight prefetch
  ffn_kernel<<<dim3(MROWS / 16), 512, 0, stream>>>(
      attn_o, x, wo_t, w1_t, w3_t, w2_t, out);
}